// Round 7
// baseline (869.376 us; speedup 1.0000x reference)
//
#include <hip/hip_runtime.h>

#define BLOCK 256
#define EPT 4   // edges per thread; 4*19 floats = 19 float4 -> aligned direct stores

typedef float v4f __attribute__((ext_vector_type(4)));
typedef int   v4i __attribute__((ext_vector_type(4)));

__device__ __forceinline__ void compute_row(
    float sx, float sy, float sz, float dx, float dy, float dz,
    const float* __restrict__ C, int p, float* __restrict__ row)
{
    // periodic shift from index: p = i*9 + j*3 + k -> (i-1, j-1, k-1)
    const float f0 = (float)(p / 9 - 1);
    const float f1 = (float)((p / 3) % 3 - 1);
    const float f2 = (float)(p % 3 - 1);

    // t_j = sum_i cell[i][j] * shift[i]
    const float tx = C[0]*f0 + C[3]*f1 + C[6]*f2;
    const float ty = C[1]*f0 + C[4]*f1 + C[7]*f2;
    const float tz = C[2]*f0 + C[5]*f1 + C[8]*f2;

    // v = pos[src] - pos[dst] + t
    const float vx = sx - dx + tx;
    const float vy = sy - dy + ty;
    const float vz = sz - dz + tz;

    const float len  = sqrtf(vx*vx + vy*vy + vz*vz);
    const float invl = 1.0f / fmaxf(len, 1e-6f);
    const float x = vx * invl, y = vy * invl, z = vz * invl;

    const float s3  = 1.7320508075688772f;
    const float s5  = 2.2360679774997896f;
    const float s15 = 3.872983346207417f;

    row[0] = len;
    row[1] = 1.0f;
    row[2] = s3 * x;
    row[3] = s3 * y;
    row[4] = s3 * z;
    row[5] = s15 * x * z;
    row[6] = s15 * x * y;
    row[7] = s5  * (y*y - 0.5f*(x*x + z*z));
    row[8] = s15 * y * z;
    row[9] = 0.5f * s15 * (z*z - x*x);

    // polynomial cutoff (P=6): 1 - 28 x^6 + 48 x^7 - 21 x^8
    const float xc = fminf(len * (1.0f/6.0f), 1.0f);
    const float x3 = xc * xc * xc;
    const float x6 = x3 * x3;
    const float cut = fmaf(x6, fmaf(xc, fmaf(-21.0f, xc, 48.0f), -28.0f), 1.0f);
    row[10] = cut;

    // bessel: sin(n*a)/(2*safe) * cut, a in [0, pi/2] -> hw sincos is accurate enough
    const float safe = fminf(fmaxf(len, 1e-6f), 6.0f);
    const float a = safe * 0.5235987755982988f;   // pi/6
    float sa, ca;
    __sincosf(a, &sa, &ca);
    const float w = cut / (2.0f * safe);
    const float two_ca = 2.0f * ca;
    float s_prev = 0.0f, s_cur = sa;
    row[11] = s_cur * w;
    #pragma unroll
    for (int n = 2; n <= 8; ++n) {
        const float s_next = two_ca * s_cur - s_prev;
        s_prev = s_cur;
        s_cur  = s_next;
        row[10 + n] = s_cur * w;
    }
}

__global__ __launch_bounds__(BLOCK) void edge_encoding_kernel(
    const float* __restrict__ pos,      // [N,3]
    const float* __restrict__ cells,    // [G,3,3] = 144 floats
    const int*  __restrict__ eidx,      // [2,E]
    const int*  __restrict__ pidx,      // [E]
    const int*  __restrict__ batch,     // [N]
    float* __restrict__ out,            // [E,19]
    int E, int aligned)                 // aligned = (E % 4 == 0)
{
    __shared__ float s_cells[144];
    const int tid = threadIdx.x;
    if (tid < 144) s_cells[tid] = cells[tid];
    __syncthreads();

    const long long e0 = ((long long)blockIdx.x * BLOCK + tid) * EPT;

    if (aligned && e0 + EPT <= (long long)E) {
        // ---- fast path: 4 edges, vector index loads, upfront gathers ----
        const v4i s4i = *reinterpret_cast<const v4i*>(eidx + e0);
        const v4i d4i = *reinterpret_cast<const v4i*>(eidx + (long long)E + e0);
        const v4i p4i = *reinterpret_cast<const v4i*>(pidx + e0);
        const int sidx[EPT] = { s4i.x, s4i.y, s4i.z, s4i.w };
        const int didx[EPT] = { d4i.x, d4i.y, d4i.z, d4i.w };
        const int pp[EPT]   = { p4i.x, p4i.y, p4i.z, p4i.w };

        float S[EPT][3], D[EPT][3];
        int   G[EPT];
        #pragma unroll
        for (int j = 0; j < EPT; ++j) {
            G[j] = batch[sidx[j]];
            S[j][0] = pos[3*sidx[j]+0]; S[j][1] = pos[3*sidx[j]+1]; S[j][2] = pos[3*sidx[j]+2];
            D[j][0] = pos[3*didx[j]+0]; D[j][1] = pos[3*didx[j]+1]; D[j][2] = pos[3*didx[j]+2];
        }

        float buf[EPT * 19];
        #pragma unroll
        for (int j = 0; j < EPT; ++j) {
            compute_row(S[j][0], S[j][1], S[j][2], D[j][0], D[j][1], D[j][2],
                        s_cells + G[j] * 9, pp[j], buf + j * 19);
        }

        // 76 floats = 19 aligned 16B vectors (thread chunk = 304 B, 16B-aligned)
        v4f* o4 = reinterpret_cast<v4f*>(out + e0 * 19);
        #pragma unroll
        for (int i = 0; i < 19; ++i) {
            v4f v;
            v.x = buf[4*i+0]; v.y = buf[4*i+1]; v.z = buf[4*i+2]; v.w = buf[4*i+3];
            __builtin_nontemporal_store(v, o4 + i);
        }
    } else {
        // ---- tail / unaligned path: per-edge scalar ----
        for (long long e = e0; e < e0 + EPT && e < (long long)E; ++e) {
            const int src = eidx[e];
            const int dst = eidx[(long long)E + e];
            const int p   = pidx[e];
            const int g   = batch[src];
            float row[19];
            compute_row(pos[3*src+0], pos[3*src+1], pos[3*src+2],
                        pos[3*dst+0], pos[3*dst+1], pos[3*dst+2],
                        s_cells + g * 9, p, row);
            float* o = out + e * 19;
            #pragma unroll
            for (int j = 0; j < 19; ++j) o[j] = row[j];
        }
    }
}

extern "C" void kernel_launch(void* const* d_in, const int* in_sizes, int n_in,
                              void* d_out, int out_size, void* d_ws, size_t ws_size,
                              hipStream_t stream) {
    const float* pos   = (const float*)d_in[0];
    const float* cells = (const float*)d_in[1];
    const int*   eidx  = (const int*)d_in[2];
    const int*   pidx  = (const int*)d_in[3];
    const int*   batch = (const int*)d_in[4];
    float* out = (float*)d_out;

    const int E = in_sizes[3];                         // periodic_index count
    const int aligned = (E % 4 == 0) ? 1 : 0;
    const int per_block = BLOCK * EPT;
    const int grid = (E + per_block - 1) / per_block;
    edge_encoding_kernel<<<grid, BLOCK, 0, stream>>>(pos, cells, eidx, pidx, batch, out, E, aligned);
}